// Round 1
// baseline (505.027 us; speedup 1.0000x reference)
//
#include <hip/hip_runtime.h>
#include <hip/hip_bf16.h>

// ---------------------------------------------------------------------------
// GIN forward (all I/O fp32):
//   2x GINConv(128->128->128, eps=0) + ReLU, L2 row-normalize,
//   per-node MLP 128->32->32->32, per-graph Gram (32x32 -> 1024),
//   per-graph MLP 1024->32->32->2.
// Internals: node features bf16, fp32 accumulate.
// This version: edge sort hoisted out of the per-layer path (CSR built once,
// neighbor lists padded to x8 with a zero-row index NN -> maskless gather),
// and aggregation fused with the 2-GEMM GINConv MLP (MFMA overlaps gather).
// ---------------------------------------------------------------------------

#define NN 131072      // nodes
#define NE 2097152     // edges
#define NG 512         // graphs
#define NB 1024        // buckets (128 nodes each)
#define ECAP 2560      // ebuf capacity per bucket (avg 2048, sigma ~45)
#define CCAP 3328      // csr capacity per bucket (avg ~2560 incl. x8 padding)
#define ECH 8192       // edges per scatter block (NE/256)

typedef unsigned short u16;
typedef unsigned int u32;
typedef __attribute__((ext_vector_type(8))) short short8;   // 8 x bf16
typedef __attribute__((ext_vector_type(4))) float f32x4;

__device__ __forceinline__ float bf2f(u16 u) {
    union { u32 i; float f; } x; x.i = ((u32)u) << 16; return x.f;
}
__device__ __forceinline__ u16 f2bf(float f) {
    union { u32 i; float f; } x; x.f = f;
    u32 r = x.i + 0x7fffu + ((x.i >> 16) & 1u);   // RNE
    return (u16)(r >> 16);
}

// ---------------- cast x: fp32 -> bf16 ----------------
__global__ __launch_bounds__(256) void cast_x(const float* __restrict__ xf,
                                              u16* __restrict__ xb) {
    int i = blockIdx.x * 256 + threadIdx.x;       // 8 floats per thread
    const float4* src = (const float4*)xf;
    float4 a = src[2 * i], b = src[2 * i + 1];
    uint4 o;
    o.x = (u32)f2bf(a.x) | ((u32)f2bf(a.y) << 16);
    o.y = (u32)f2bf(a.z) | ((u32)f2bf(a.w) << 16);
    o.z = (u32)f2bf(b.x) | ((u32)f2bf(b.y) << 16);
    o.w = (u32)f2bf(b.z) | ((u32)f2bf(b.w) << 16);
    ((uint4*)xb)[i] = o;
}

// ---------------- zero the pad row (index NN) of both feature buffers ------
__global__ __launch_bounds__(128) void zero_tail(u16* __restrict__ X0,
                                                 u16* __restrict__ H1) {
    int t = threadIdx.x;
    u32* a = (u32*)(X0 + (size_t)NN * 128);
    u32* b = (u32*)(H1 + (size_t)NN * 128);
    if (t < 64) a[t] = 0; else b[t - 64] = 0;
}

// ---------------- cursor init: cursor[b] = b * ECAP ----------------
__global__ __launch_bounds__(256) void init_cursor(int* __restrict__ cursor) {
    int b = blockIdx.x * 256 + threadIdx.x;
    cursor[b] = b * ECAP;
}

// ---------------- direct scatter into bucket regions ----------------
// ebuf[bucket region b*ECAP ...] = (src << 7) | (dst & 127)
__global__ __launch_bounds__(256) void bin_scatter(const int* __restrict__ gsrc,
                                                   const int* __restrict__ gdst,
                                                   int* __restrict__ cursor,
                                                   u32* __restrict__ ebuf) {
    __shared__ int lc[NB];   // local counts
    __shared__ int rb[NB];   // reserved run base (global)
    __shared__ int lb[NB];   // local bump
    int t = threadIdx.x;
    for (int i = 0; i < 4; ++i) lc[t + i * 256] = 0;
    __syncthreads();
    int base = blockIdx.x * ECH;
    for (int i = 0; i < ECH / 256; ++i) {
        int d = gdst[base + i * 256 + t];
        atomicAdd(&lc[d >> 7], 1);
    }
    __syncthreads();
    for (int i = 0; i < 4; ++i) {
        int b = t + i * 256;
        int c = lc[b];
        rb[b] = c ? atomicAdd(&cursor[b], c) : 0;
        lb[b] = 0;
    }
    __syncthreads();
    for (int i = 0; i < ECH / 256; ++i) {
        int idx = base + i * 256 + t;
        int d = gdst[idx];
        int s = gsrc[idx];
        int b = d >> 7;
        int o = atomicAdd(&lb[b], 1);
        ebuf[rb[b] + o] = ((u32)s << 7) | (u32)(d & 127);
    }
}

// ---------------- per-bucket counting sort -> padded CSR (ONCE) ------------
// csr segment per node is 16B-aligned (start multiple of 8 entries) and
// padded to a multiple of 8 with index NN (zero feature row) -> the gather
// needs no tail masking at all. deg[] stores the PADDED count.
__global__ __launch_bounds__(512) void csr_sort(const u32* __restrict__ ebuf,
                                                const int* __restrict__ cursor,
                                                int* __restrict__ csr,
                                                int* __restrict__ start,
                                                int* __restrict__ deg) {
    __shared__ int lcnt[128];
    __shared__ int lstart[128];
    __shared__ int lofs[128];
    int t = threadIdx.x, lane = t & 63, wave = t >> 6;
    int bkt = blockIdx.x;
    int e0 = bkt * ECAP;
    int n = cursor[bkt] - e0;
    if (t < 128) lcnt[t] = 0;
    __syncthreads();
    for (int j = t; j < n; j += 512)
        atomicAdd(&lcnt[ebuf[e0 + j] & 127], 1);
    __syncthreads();
    if (wave == 0) {                              // excl scan of rounded counts
        int c0 = lcnt[2 * lane], c1 = lcnt[2 * lane + 1];
        int r0 = (c0 + 7) & ~7, r1 = (c1 + 7) & ~7;
        int s = r0 + r1, e = s;
        for (int o = 1; o < 64; o <<= 1) {
            int u = __shfl_up(e, o, 64);
            if (lane >= o) e += u;
        }
        int excl = e - s;
        lstart[2 * lane] = excl;          lofs[2 * lane] = excl;
        lstart[2 * lane + 1] = excl + r0; lofs[2 * lane + 1] = excl + r0;
    }
    __syncthreads();
    for (int j = t; j < n; j += 512) {
        u32 e = ebuf[e0 + j];
        int node = e & 127;
        int pos = atomicAdd(&lofs[node], 1);
        csr[bkt * CCAP + pos] = (int)(e >> 7);
    }
    __syncthreads();
    if (t < 128) {
        int c = lcnt[t];
        int cp = (c + 7) & ~7;
        int base = bkt * CCAP + lstart[t];
        for (int q = c; q < cp; ++q) csr[base + q] = NN;   // pad -> zero row
        start[bkt * 128 + t] = base;
        deg[bkt * 128 + t] = cp;
    }
}

// ---------------- weight transpose + cast: Wt[n][k] = (bf16)W[k][n] --------
__global__ __launch_bounds__(256) void transpose_w(const float* a, const float* b,
                                                   const float* c, const float* d, u16* Wt) {
    const float* w = (blockIdx.x == 0) ? a : (blockIdx.x == 1) ? b : (blockIdx.x == 2) ? c : d;
    u16* o = Wt + blockIdx.x * 16384;
    for (int i = 0; i < 64; ++i) {
        int idx = threadIdx.x + i * 256;
        o[(idx & 127) * 128 + (idx >> 7)] = f2bf(w[idx]);
    }
}

// ---------------- small-MLP weight transpose: n-major bf16 ----------------
__global__ __launch_bounds__(256) void transpose_small(const float* Ws1, const float* Ws2,
                                                       const float* Ws3, u16* Wsm) {
    int t = threadIdx.x;
    for (int i = 0; i < 16; ++i) {
        int idx = t + i * 256;
        int k = idx >> 5, n = idx & 31;
        Wsm[n * 128 + k] = f2bf(Ws1[idx]);
    }
    for (int i = 0; i < 4; ++i) {
        int idx = t + i * 256;
        int k = idx >> 5, n = idx & 31;
        Wsm[4096 + n * 32 + k] = f2bf(Ws2[idx]);
        Wsm[5120 + n * 32 + k] = f2bf(Ws3[idx]);
    }
}

// ---------------- FUSED: aggregate (CSR gather) + 2-GEMM GINConv MLP -------
// Block = 128 nodes, 512 threads (8 waves x 16 nodes). LDS 69.6KB -> 2 blk/CU.
// Gather: maskless always-8-wide (padded CSR), acc in registers, -> As bf16.
// Then the proven gemm2_relu MFMA sequence (W2 reuses W1's LDS).
__global__ __launch_bounds__(512, 4) void agg_mlp(const u16* __restrict__ X,
                                                  const int* __restrict__ csr,
                                                  const int* __restrict__ start,
                                                  const int* __restrict__ deg,
                                                  const u16* __restrict__ Wt1,
                                                  const u16* __restrict__ Wt2,
                                                  const float* __restrict__ b1,
                                                  const float* __restrict__ b2,
                                                  u16* __restrict__ C) {
    __shared__ u16 As[128][136];    // aggregated tile, then h1 (wave-private rows)
    __shared__ u16 Ws[128][136];    // W1, then W2
    int tid = threadIdx.x, lane = tid & 63, wave = tid >> 6;
    int quad = lane >> 4, l16 = lane & 15;
    size_t rowBase = (size_t)blockIdx.x * 128;
    const u32* Xu = (const u32*)X;

    // stage W1 -> LDS (completes long before the post-gather barrier)
#pragma unroll
    for (int i = 0; i < 4; ++i) {
        int c = tid + i * 512;
        int r = c >> 4, co = (c & 15) << 3;
        *(uint4*)&Ws[r][co] = *(const uint4*)(Wt1 + r * 128 + co);
    }

    // gather: each wave owns 16 rows; self term + maskless 8-wide neighbor sum
    for (int i = 0; i < 16; ++i) {
        int row = (int)rowBase + wave * 16 + i;
        u32 v = Xu[(row << 6) + lane];
        float a0 = bf2f((u16)v), a1 = bf2f((u16)(v >> 16));
        int st = start[row], de = deg[row];     // de is padded to x8
        const int* ip = csr + st;               // 16B-aligned segment
        for (int p = 0; p < de; p += 8) {
            int4 i0 = *(const int4*)(ip + p);
            int4 i1 = *(const int4*)(ip + p + 4);
            int s[8] = {i0.x, i0.y, i0.z, i0.w, i1.x, i1.y, i1.z, i1.w};
            u32 w[8];
#pragma unroll
            for (int k = 0; k < 8; ++k) w[k] = Xu[(s[k] << 6) + lane];
#pragma unroll
            for (int k = 0; k < 8; ++k) {
                a0 += bf2f((u16)w[k]);
                a1 += bf2f((u16)(w[k] >> 16));
            }
        }
        *(u32*)&As[wave * 16 + i][2 * lane] = (u32)f2bf(a0) | ((u32)f2bf(a1) << 16);
    }
    __syncthreads();                 // As complete, Ws(W1) staged

    // issue W2 global loads now; they complete under gemm1's MFMAs
    uint4 w2r[4];
#pragma unroll
    for (int i = 0; i < 4; ++i) {
        int c = tid + i * 512;
        w2r[i] = *(const uint4*)(Wt2 + (c >> 4) * 128 + ((c & 15) << 3));
    }

    // gemm1: h1 = relu(As @ W1 + b1), back into As (wave-private rows)
    f32x4 acc[8];
#pragma unroll
    for (int t = 0; t < 8; ++t) acc[t] = (f32x4){0.f, 0.f, 0.f, 0.f};
#pragma unroll
    for (int c = 0; c < 4; ++c) {
        short8 a = *(const short8*)&As[wave * 16 + l16][c * 32 + quad * 8];
#pragma unroll
        for (int t = 0; t < 8; ++t) {
            short8 b = *(const short8*)&Ws[t * 16 + l16][c * 32 + quad * 8];
            acc[t] = __builtin_amdgcn_mfma_f32_16x16x32_bf16(a, b, acc[t], 0, 0, 0);
        }
    }
#pragma unroll
    for (int t = 0; t < 8; ++t) {
        int col = t * 16 + l16;
        float bv = b1[col];
#pragma unroll
        for (int r = 0; r < 4; ++r)
            As[wave * 16 + quad * 4 + r][col] = f2bf(fmaxf(acc[t][r] + bv, 0.f));
    }
    __syncthreads();                 // all waves done reading W1 + their A rows

    // overwrite Ws with W2 (registers already in flight)
#pragma unroll
    for (int i = 0; i < 4; ++i) {
        int c = tid + i * 512;
        *(uint4*)&Ws[c >> 4][(c & 15) << 3] = w2r[i];
    }
    __syncthreads();                 // Ws is now W2; As rows are wave-private h1

    // gemm2: C = relu(h1 @ W2 + b2)
    f32x4 acc2[8];
#pragma unroll
    for (int t = 0; t < 8; ++t) acc2[t] = (f32x4){0.f, 0.f, 0.f, 0.f};
#pragma unroll
    for (int c = 0; c < 4; ++c) {
        short8 a = *(const short8*)&As[wave * 16 + l16][c * 32 + quad * 8];
#pragma unroll
        for (int t = 0; t < 8; ++t) {
            short8 b = *(const short8*)&Ws[t * 16 + l16][c * 32 + quad * 8];
            acc2[t] = __builtin_amdgcn_mfma_f32_16x16x32_bf16(a, b, acc2[t], 0, 0, 0);
        }
    }
#pragma unroll
    for (int t = 0; t < 8; ++t) {
        int col = t * 16 + l16;
        float bv = b2[col];
#pragma unroll
        for (int r = 0; r < 4; ++r) {
            int row = wave * 16 + quad * 4 + r;
            C[(rowBase + row) * 128 + col] = f2bf(fmaxf(acc2[t][r] + bv, 0.f));
        }
    }
}

// ---------------- MFMA node MLP: normalize + 128->32->32->32 ----------------
__global__ __launch_bounds__(256) void norm_mlp_mfma(const u16* __restrict__ X,
                                                     const u16* __restrict__ Wsm,
                                                     const float* __restrict__ bs1,
                                                     const float* __restrict__ bs2,
                                                     const float* __restrict__ bs3,
                                                     float* __restrict__ S) {
    __shared__ u16 As[64][136];      // normalized rows (bf16)
    __shared__ u16 W1s[32][136];     // Ws1t 32x128
    __shared__ u16 W23s[2][32][40];  // Ws2t, Ws3t 32x32
    __shared__ u16 H[64][40];        // hidden (wave-private 16-row strips)
    int tid = threadIdx.x, lane = tid & 63, wave = tid >> 6;
    int quad = lane >> 4, l16 = lane & 15;
    size_t rowBase = (size_t)blockIdx.x * 64;

#pragma unroll
    for (int i = 0; i < 2; ++i) {
        int c = tid + i * 256;
        int r = c >> 4, co = (c & 15) << 3;
        *(uint4*)&W1s[r][co] = *(const uint4*)(Wsm + r * 128 + co);
    }
    {
        int which = tid >> 7, cc = tid & 127;
        int r = cc >> 2, co = (cc & 3) << 3;
        *(uint4*)&W23s[which][r][co] = *(const uint4*)(Wsm + 4096 + which * 1024 + r * 32 + co);
    }

    const u32* Xu = (const u32*)X;
    for (int i = 0; i < 16; ++i) {
        int row = wave * 16 + i;
        u32 v = Xu[(rowBase + row) * 64 + lane];
        float f0 = bf2f((u16)v), f1 = bf2f((u16)(v >> 16));
        float ss = f0 * f0 + f1 * f1;
        for (int o = 1; o < 64; o <<= 1) ss += __shfl_xor(ss, o, 64);
        float inv = 1.0f / fmaxf(sqrtf(ss), 1e-12f);
        *(u32*)&As[row][2 * lane] = (u32)f2bf(f0 * inv) | ((u32)f2bf(f1 * inv) << 16);
    }
    __syncthreads();

    f32x4 acc[2];
    acc[0] = (f32x4){0.f, 0.f, 0.f, 0.f};
    acc[1] = (f32x4){0.f, 0.f, 0.f, 0.f};
#pragma unroll
    for (int c = 0; c < 4; ++c) {
        short8 a = *(const short8*)&As[wave * 16 + l16][c * 32 + quad * 8];
#pragma unroll
        for (int t = 0; t < 2; ++t) {
            short8 b = *(const short8*)&W1s[t * 16 + l16][c * 32 + quad * 8];
            acc[t] = __builtin_amdgcn_mfma_f32_16x16x32_bf16(a, b, acc[t], 0, 0, 0);
        }
    }
#pragma unroll
    for (int t = 0; t < 2; ++t) {
        int col = t * 16 + l16;
        float bv = bs1[col];
#pragma unroll
        for (int r = 0; r < 4; ++r)
            H[wave * 16 + quad * 4 + r][col] = f2bf(fmaxf(acc[t][r] + bv, 0.f));
    }
    __syncthreads();

    f32x4 acc2[2];
    acc2[0] = (f32x4){0.f, 0.f, 0.f, 0.f};
    acc2[1] = (f32x4){0.f, 0.f, 0.f, 0.f};
    {
        short8 a = *(const short8*)&H[wave * 16 + l16][quad * 8];
#pragma unroll
        for (int t = 0; t < 2; ++t) {
            short8 b = *(const short8*)&W23s[0][t * 16 + l16][quad * 8];
            acc2[t] = __builtin_amdgcn_mfma_f32_16x16x32_bf16(a, b, acc2[t], 0, 0, 0);
        }
    }
    __syncthreads();
#pragma unroll
    for (int t = 0; t < 2; ++t) {
        int col = t * 16 + l16;
        float bv = bs2[col];
#pragma unroll
        for (int r = 0; r < 4; ++r)
            H[wave * 16 + quad * 4 + r][col] = f2bf(fmaxf(acc2[t][r] + bv, 0.f));
    }
    __syncthreads();

    f32x4 acc3[2];
    acc3[0] = (f32x4){0.f, 0.f, 0.f, 0.f};
    acc3[1] = (f32x4){0.f, 0.f, 0.f, 0.f};
    {
        short8 a = *(const short8*)&H[wave * 16 + l16][quad * 8];
#pragma unroll
        for (int t = 0; t < 2; ++t) {
            short8 b = *(const short8*)&W23s[1][t * 16 + l16][quad * 8];
            acc3[t] = __builtin_amdgcn_mfma_f32_16x16x32_bf16(a, b, acc3[t], 0, 0, 0);
        }
    }
#pragma unroll
    for (int t = 0; t < 2; ++t) {
        int col = t * 16 + l16;
        float bv = bs3[col];
#pragma unroll
        for (int r = 0; r < 4; ++r) {
            int row = wave * 16 + quad * 4 + r;
            S[(rowBase + row) * 32 + col] = fmaxf(acc3[t][r] + bv, 0.f);
        }
    }
}

// ---------------- per-graph Gram: out[g][f][e] = sum_n S[g,n,f]*S[g,n,e] ----
__global__ __launch_bounds__(256) void gram(const float* __restrict__ S,
                                            float* __restrict__ out) {
    __shared__ float Sg[256 * 32];
    int t = threadIdx.x, g = blockIdx.x;
    const float4* src = (const float4*)(S + (size_t)g * 8192);
    float4* dst = (float4*)Sg;
    for (int i = 0; i < 8; ++i) dst[t + i * 256] = src[t + i * 256];
    __syncthreads();

    int f = t >> 3, e0 = (t & 7) << 2;
    float4 a = {0.f, 0.f, 0.f, 0.f};
    for (int n = 0; n < 256; ++n) {
        float sf = Sg[n * 32 + f];
        float4 se = *(const float4*)&Sg[n * 32 + e0];
        a.x += sf * se.x; a.y += sf * se.y; a.z += sf * se.z; a.w += sf * se.w;
    }
    *(float4*)(out + (size_t)g * 1024 + f * 32 + e0) = a;
}

// ---------------- per-graph MLP: 1024->32->32->2 (fp32) ----------------
__global__ __launch_bounds__(256) void graph_mlp(const float* __restrict__ HH,
                                                 const float* Wm1, const float* bm1,
                                                 const float* Wm2, const float* bm2,
                                                 const float* Wm3, const float* bm3,
                                                 float* __restrict__ out) {
    __shared__ float hh[1024];
    __shared__ float red[256];
    __shared__ float o1[32];
    __shared__ float o2[32];
    int t = threadIdx.x, g = blockIdx.x;
    ((float4*)hh)[t] = ((const float4*)(HH + (size_t)g * 1024))[t];
    __syncthreads();

    int j = t & 31, part = t >> 5;
    float p = 0.f;
    for (int i = 0; i < 128; ++i) { int k = part * 128 + i; p += hh[k] * Wm1[k * 32 + j]; }
    red[t] = p;
    __syncthreads();
    if (t < 32) {
        float s = 0.f;
        for (int q = 0; q < 8; ++q) s += red[q * 32 + t];
        o1[t] = fmaxf(s + bm1[t], 0.f);
    }
    __syncthreads();
    if (t < 32) {
        float s = 0.f;
        for (int k = 0; k < 32; ++k) s += o1[k] * Wm2[k * 32 + t];
        o2[t] = fmaxf(s + bm2[t], 0.f);
    }
    __syncthreads();
    if (t < 2) {
        float s = 0.f;
        for (int k = 0; k < 32; ++k) s += o2[k] * Wm3[k * 2 + t];
        out[524288 + g * 2 + t] = fmaxf(s + bm3[t], 0.f);
    }
}

// ---------------------------------------------------------------------------
extern "C" void kernel_launch(void* const* d_in, const int* in_sizes, int n_in,
                              void* d_out, int out_size, void* d_ws, size_t ws_size,
                              hipStream_t stream) {
    const float* x   = (const float*)d_in[0];
    const int*   ei  = (const int*)d_in[1];
    const float* W1a = (const float*)d_in[2];  const float* b1a = (const float*)d_in[3];
    const float* W2a = (const float*)d_in[4];  const float* b2a = (const float*)d_in[5];
    const float* W1b = (const float*)d_in[6];  const float* b1b = (const float*)d_in[7];
    const float* W2b = (const float*)d_in[8];  const float* b2b = (const float*)d_in[9];
    const float* Ws1 = (const float*)d_in[10]; const float* bs1 = (const float*)d_in[11];
    const float* Ws2 = (const float*)d_in[12]; const float* bs2 = (const float*)d_in[13];
    const float* Ws3 = (const float*)d_in[14]; const float* bs3 = (const float*)d_in[15];
    const float* Wm1 = (const float*)d_in[16]; const float* bm1 = (const float*)d_in[17];
    const float* Wm2 = (const float*)d_in[18]; const float* bm2 = (const float*)d_in[19];
    const float* Wm3 = (const float*)d_in[20]; const float* bm3 = (const float*)d_in[21];
    float* out = (float*)d_out;

    const int* gsrc = ei;
    const int* gdst = ei + NE;

    char* ws = (char*)d_ws;
    size_t off = 0;
    auto alloc = [&](size_t bytes) { size_t r = off; off = (off + bytes + 255) & ~(size_t)255; return r; };
    int*  cursor = (int*)(ws + alloc((size_t)NB * 4));
    u32*  ebuf   = (u32*)(ws + alloc((size_t)NB * ECAP * 4));   // 10.5 MB
    int*  csr    = (int*)(ws + alloc((size_t)NB * CCAP * 4));   // 13.6 MB (adjacent)
    int*  stA    = (int*)(ws + alloc((size_t)NN * 4));
    int*  dgA    = (int*)(ws + alloc((size_t)NN * 4));
    u16*  Wt     = (u16*)(ws + alloc(4 * 16384 * 2));
    u16*  Wsm    = (u16*)(ws + alloc(6144 * 2));
    u16*  X0     = (u16*)(ws + alloc((size_t)(NN + 1) * 128 * 2));  // +zero row
    u16*  H1     = (u16*)(ws + alloc((size_t)(NN + 1) * 128 * 2));  // +zero row
    float* S     = (float*)ebuf;   // 16.78MB alias over ebuf+csr (dead by then)
    (void)ws_size; (void)n_in; (void)in_sizes; (void)out_size;

    // ---- build padded CSR once (edge structure identical for both layers) ----
    init_cursor<<<NB / 256, 256, 0, stream>>>(cursor);
    bin_scatter<<<NE / ECH, 256, 0, stream>>>(gsrc, gdst, cursor, ebuf);
    csr_sort<<<NB, 512, 0, stream>>>(ebuf, cursor, csr, stA, dgA);

    // ---- casts / weight prep ----
    cast_x<<<NN * 128 / (256 * 8), 256, 0, stream>>>(x, X0);
    zero_tail<<<1, 128, 0, stream>>>(X0, H1);
    transpose_w<<<4, 256, 0, stream>>>(W1a, W2a, W1b, W2b, Wt);
    transpose_small<<<1, 256, 0, stream>>>(Ws1, Ws2, Ws3, Wsm);

    // ---- fused GINConv layers ----
    agg_mlp<<<NN / 128, 512, 0, stream>>>(X0, csr, stA, dgA,
                                          Wt + 0 * 16384, Wt + 1 * 16384, b1a, b2a, H1);
    agg_mlp<<<NN / 128, 512, 0, stream>>>(H1, csr, stA, dgA,
                                          Wt + 2 * 16384, Wt + 3 * 16384, b1b, b2b, X0);

    // ---- tail: MFMA node MLP, Gram -> out, graph MLP ----
    norm_mlp_mfma<<<NN / 64, 256, 0, stream>>>(X0, Wsm, bs1, bs2, bs3, S);
    gram<<<NG, 256, 0, stream>>>(S, out);
    graph_mlp<<<NG, 256, 0, stream>>>(out, Wm1, bm1, Wm2, bm2, Wm3, bm3, out);
}

// Round 2
// 478.541 us; speedup vs baseline: 1.0553x; 1.0553x over previous
//
#include <hip/hip_runtime.h>
#include <hip/hip_bf16.h>

// ---------------------------------------------------------------------------
// GIN forward (all I/O fp32):
//   2x GINConv(128->128->128, eps=0) + ReLU, L2 row-normalize,
//   per-node MLP 128->32->32->32, per-graph Gram (32x32 -> 1024),
//   per-graph MLP 1024->32->32->2.
// Internals: node features bf16, fp32 accumulate.
// R2: CSR built once (padded x8 with zero-row NN), aggregation fused with the
// 2-GEMM GINConv MLP. Fix vs R1: neighbor indices are cooperatively staged
// into LDS (aliased over As) before the gather -- R1 read them as wave-uniform
// global int4 (serial global->global chain, latency-bound: VALUBusy 31%).
// Gather accumulates 16 rows/wave in registers, then writes As post-barrier.
// ---------------------------------------------------------------------------

#define NN 131072      // nodes
#define NE 2097152     // edges
#define NG 512         // graphs
#define NB 1024        // buckets (128 nodes each)
#define ECAP 2560      // ebuf capacity per bucket (avg 2048, sigma ~45)
#define CCAP 3328      // csr capacity per bucket (avg ~2560 incl. x8 padding)
#define ECH 8192       // edges per scatter block (NE/256)

typedef unsigned short u16;
typedef unsigned int u32;
typedef __attribute__((ext_vector_type(8))) short short8;   // 8 x bf16
typedef __attribute__((ext_vector_type(4))) float f32x4;

__device__ __forceinline__ float bf2f(u16 u) {
    union { u32 i; float f; } x; x.i = ((u32)u) << 16; return x.f;
}
__device__ __forceinline__ u16 f2bf(float f) {
    union { u32 i; float f; } x; x.f = f;
    u32 r = x.i + 0x7fffu + ((x.i >> 16) & 1u);   // RNE
    return (u16)(r >> 16);
}

// ---------------- cast x: fp32 -> bf16 ----------------
__global__ __launch_bounds__(256) void cast_x(const float* __restrict__ xf,
                                              u16* __restrict__ xb) {
    int i = blockIdx.x * 256 + threadIdx.x;       // 8 floats per thread
    const float4* src = (const float4*)xf;
    float4 a = src[2 * i], b = src[2 * i + 1];
    uint4 o;
    o.x = (u32)f2bf(a.x) | ((u32)f2bf(a.y) << 16);
    o.y = (u32)f2bf(a.z) | ((u32)f2bf(a.w) << 16);
    o.z = (u32)f2bf(b.x) | ((u32)f2bf(b.y) << 16);
    o.w = (u32)f2bf(b.z) | ((u32)f2bf(b.w) << 16);
    ((uint4*)xb)[i] = o;
}

// ---------------- zero the pad row (index NN) of both feature buffers ------
__global__ __launch_bounds__(128) void zero_tail(u16* __restrict__ X0,
                                                 u16* __restrict__ H1) {
    int t = threadIdx.x;
    u32* a = (u32*)(X0 + (size_t)NN * 128);
    u32* b = (u32*)(H1 + (size_t)NN * 128);
    if (t < 64) a[t] = 0; else b[t - 64] = 0;
}

// ---------------- cursor init: cursor[b] = b * ECAP ----------------
__global__ __launch_bounds__(256) void init_cursor(int* __restrict__ cursor) {
    int b = blockIdx.x * 256 + threadIdx.x;
    cursor[b] = b * ECAP;
}

// ---------------- direct scatter into bucket regions ----------------
// ebuf[bucket region b*ECAP ...] = (src << 7) | (dst & 127)
__global__ __launch_bounds__(256) void bin_scatter(const int* __restrict__ gsrc,
                                                   const int* __restrict__ gdst,
                                                   int* __restrict__ cursor,
                                                   u32* __restrict__ ebuf) {
    __shared__ int lc[NB];   // local counts
    __shared__ int rb[NB];   // reserved run base (global)
    __shared__ int lb[NB];   // local bump
    int t = threadIdx.x;
    for (int i = 0; i < 4; ++i) lc[t + i * 256] = 0;
    __syncthreads();
    int base = blockIdx.x * ECH;
    for (int i = 0; i < ECH / 256; ++i) {
        int d = gdst[base + i * 256 + t];
        atomicAdd(&lc[d >> 7], 1);
    }
    __syncthreads();
    for (int i = 0; i < 4; ++i) {
        int b = t + i * 256;
        int c = lc[b];
        rb[b] = c ? atomicAdd(&cursor[b], c) : 0;
        lb[b] = 0;
    }
    __syncthreads();
    for (int i = 0; i < ECH / 256; ++i) {
        int idx = base + i * 256 + t;
        int d = gdst[idx];
        int s = gsrc[idx];
        int b = d >> 7;
        int o = atomicAdd(&lb[b], 1);
        ebuf[rb[b] + o] = ((u32)s << 7) | (u32)(d & 127);
    }
}

// ---------------- per-bucket counting sort -> padded CSR (ONCE) ------------
// csr segment per node is 16B-aligned (start multiple of 8 entries) and
// padded to a multiple of 8 with index NN (zero feature row) -> the gather
// needs no tail masking at all. deg[] stores the PADDED count.
// bcnt[bkt] = total padded entries in the bucket (for LDS staging).
__global__ __launch_bounds__(512) void csr_sort(const u32* __restrict__ ebuf,
                                                const int* __restrict__ cursor,
                                                int* __restrict__ csr,
                                                int* __restrict__ start,
                                                int* __restrict__ deg,
                                                int* __restrict__ bcnt) {
    __shared__ int lcnt[128];
    __shared__ int lstart[128];
    __shared__ int lofs[128];
    int t = threadIdx.x, lane = t & 63, wave = t >> 6;
    int bkt = blockIdx.x;
    int e0 = bkt * ECAP;
    int n = cursor[bkt] - e0;
    if (t < 128) lcnt[t] = 0;
    __syncthreads();
    for (int j = t; j < n; j += 512)
        atomicAdd(&lcnt[ebuf[e0 + j] & 127], 1);
    __syncthreads();
    if (wave == 0) {                              // excl scan of rounded counts
        int c0 = lcnt[2 * lane], c1 = lcnt[2 * lane + 1];
        int r0 = (c0 + 7) & ~7, r1 = (c1 + 7) & ~7;
        int s = r0 + r1, e = s;
        for (int o = 1; o < 64; o <<= 1) {
            int u = __shfl_up(e, o, 64);
            if (lane >= o) e += u;
        }
        int excl = e - s;
        lstart[2 * lane] = excl;          lofs[2 * lane] = excl;
        lstart[2 * lane + 1] = excl + r0; lofs[2 * lane + 1] = excl + r0;
        if (lane == 63) bcnt[bkt] = e;            // total padded count
    }
    __syncthreads();
    for (int j = t; j < n; j += 512) {
        u32 e = ebuf[e0 + j];
        int node = e & 127;
        int pos = atomicAdd(&lofs[node], 1);
        csr[bkt * CCAP + pos] = (int)(e >> 7);
    }
    __syncthreads();
    if (t < 128) {
        int c = lcnt[t];
        int cp = (c + 7) & ~7;
        int base = bkt * CCAP + lstart[t];
        for (int q = c; q < cp; ++q) csr[base + q] = NN;   // pad -> zero row
        start[bkt * 128 + t] = base;
        deg[bkt * 128 + t] = cp;
    }
}

// ---------------- weight transpose + cast: Wt[n][k] = (bf16)W[k][n] --------
__global__ __launch_bounds__(256) void transpose_w(const float* a, const float* b,
                                                   const float* c, const float* d, u16* Wt) {
    const float* w = (blockIdx.x == 0) ? a : (blockIdx.x == 1) ? b : (blockIdx.x == 2) ? c : d;
    u16* o = Wt + blockIdx.x * 16384;
    for (int i = 0; i < 64; ++i) {
        int idx = threadIdx.x + i * 256;
        o[(idx & 127) * 128 + (idx >> 7)] = f2bf(w[idx]);
    }
}

// ---------------- small-MLP weight transpose: n-major bf16 ----------------
__global__ __launch_bounds__(256) void transpose_small(const float* Ws1, const float* Ws2,
                                                       const float* Ws3, u16* Wsm) {
    int t = threadIdx.x;
    for (int i = 0; i < 16; ++i) {
        int idx = t + i * 256;
        int k = idx >> 5, n = idx & 31;
        Wsm[n * 128 + k] = f2bf(Ws1[idx]);
    }
    for (int i = 0; i < 4; ++i) {
        int idx = t + i * 256;
        int k = idx >> 5, n = idx & 31;
        Wsm[4096 + n * 32 + k] = f2bf(Ws2[idx]);
        Wsm[5120 + n * 32 + k] = f2bf(Ws3[idx]);
    }
}

// ---------------- FUSED: aggregate (LDS-staged CSR gather) + 2-GEMM MLP ----
// Block = 128 nodes (one bucket), 512 threads (8 waves x 16 nodes).
// Phase 1: stream bucket's CSR into LDS (aliased over As), coalesced.
// Phase 2: gather -- indices from LDS broadcast, 8 global loads in flight,
//          16 rows/wave accumulated in registers.
// Phase 3: write As, then the proven 2-GEMM MFMA sequence (W2 reuses W1 LDS).
__global__ __launch_bounds__(512, 4) void agg_mlp(const u16* __restrict__ X,
                                                  const int* __restrict__ csr,
                                                  const int* __restrict__ start,
                                                  const int* __restrict__ deg,
                                                  const int* __restrict__ bcnt,
                                                  const u16* __restrict__ Wt1,
                                                  const u16* __restrict__ Wt2,
                                                  const float* __restrict__ b1,
                                                  const float* __restrict__ b2,
                                                  u16* __restrict__ C) {
    __shared__ __align__(16) u16 As[128][136];  // idx stage -> agg tile -> h1
    __shared__ __align__(16) u16 Ws[128][136];  // W1, then W2
    int tid = threadIdx.x, lane = tid & 63, wave = tid >> 6;
    int quad = lane >> 4, l16 = lane & 15;
    int bkt = blockIdx.x;
    size_t rowBase = (size_t)bkt * 128;
    const u32* Xu = (const u32*)X;
    int* Ls = (int*)&As[0][0];                  // index staging area (<=13.3KB)

    // stage W1 -> LDS
#pragma unroll
    for (int i = 0; i < 4; ++i) {
        int c = tid + i * 512;
        int r = c >> 4, co = (c & 15) << 3;
        *(uint4*)&Ws[r][co] = *(const uint4*)(Wt1 + r * 128 + co);
    }
    // stage this bucket's CSR segment -> LDS (coalesced int4 stream)
    {
        int n4 = bcnt[bkt] >> 2;                // padded total / 4 (exact)
        const int4* g4 = (const int4*)(csr + bkt * CCAP);
        int4* l4 = (int4*)Ls;
        for (int j = tid; j < n4; j += 512) l4[j] = g4[j];
    }
    __syncthreads();

    // gather: each wave owns 16 rows; self term + maskless 8-wide neighbor sum
    float a0[16], a1[16];
#pragma unroll
    for (int i = 0; i < 16; ++i) {
        int row = (int)rowBase + wave * 16 + i;
        u32 v = Xu[(row << 6) + lane];
        a0[i] = bf2f((u16)v);
        a1[i] = bf2f((u16)(v >> 16));
        int st = start[row] - bkt * CCAP;       // LDS-relative, multiple of 8
        int de = deg[row];                      // padded to x8
        for (int p = 0; p < de; p += 8) {
            int4 i0 = *(const int4*)&Ls[st + p];
            int4 i1 = *(const int4*)&Ls[st + p + 4];
            int s[8] = {i0.x, i0.y, i0.z, i0.w, i1.x, i1.y, i1.z, i1.w};
            u32 w[8];
#pragma unroll
            for (int k = 0; k < 8; ++k) w[k] = Xu[(s[k] << 6) + lane];
#pragma unroll
            for (int k = 0; k < 8; ++k) {
                a0[i] += bf2f((u16)w[k]);
                a1[i] += bf2f((u16)(w[k] >> 16));
            }
        }
    }
    __syncthreads();                 // all waves done reading Ls

    // write aggregated rows into As (packed u32)
#pragma unroll
    for (int i = 0; i < 16; ++i)
        *(u32*)&As[wave * 16 + i][2 * lane] =
            (u32)f2bf(a0[i]) | ((u32)f2bf(a1[i]) << 16);

    // issue W2 global loads now; they complete under gemm1's MFMAs
    uint4 w2r[4];
#pragma unroll
    for (int i = 0; i < 4; ++i) {
        int c = tid + i * 512;
        w2r[i] = *(const uint4*)(Wt2 + (c >> 4) * 128 + ((c & 15) << 3));
    }
    __syncthreads();                 // As complete, Ws(W1) staged

    // gemm1: h1 = relu(As @ W1 + b1), back into As (wave-private rows)
    f32x4 acc[8];
#pragma unroll
    for (int t = 0; t < 8; ++t) acc[t] = (f32x4){0.f, 0.f, 0.f, 0.f};
#pragma unroll
    for (int c = 0; c < 4; ++c) {
        short8 a = *(const short8*)&As[wave * 16 + l16][c * 32 + quad * 8];
#pragma unroll
        for (int t = 0; t < 8; ++t) {
            short8 b = *(const short8*)&Ws[t * 16 + l16][c * 32 + quad * 8];
            acc[t] = __builtin_amdgcn_mfma_f32_16x16x32_bf16(a, b, acc[t], 0, 0, 0);
        }
    }
#pragma unroll
    for (int t = 0; t < 8; ++t) {
        int col = t * 16 + l16;
        float bv = b1[col];
#pragma unroll
        for (int r = 0; r < 4; ++r)
            As[wave * 16 + quad * 4 + r][col] = f2bf(fmaxf(acc[t][r] + bv, 0.f));
    }
    __syncthreads();                 // all waves done reading W1 + their A rows

    // overwrite Ws with W2 (registers already in flight)
#pragma unroll
    for (int i = 0; i < 4; ++i) {
        int c = tid + i * 512;
        *(uint4*)&Ws[c >> 4][(c & 15) << 3] = w2r[i];
    }
    __syncthreads();                 // Ws is now W2; As rows are wave-private h1

    // gemm2: C = relu(h1 @ W2 + b2)
    f32x4 acc2[8];
#pragma unroll
    for (int t = 0; t < 8; ++t) acc2[t] = (f32x4){0.f, 0.f, 0.f, 0.f};
#pragma unroll
    for (int c = 0; c < 4; ++c) {
        short8 a = *(const short8*)&As[wave * 16 + l16][c * 32 + quad * 8];
#pragma unroll
        for (int t = 0; t < 8; ++t) {
            short8 b = *(const short8*)&Ws[t * 16 + l16][c * 32 + quad * 8];
            acc2[t] = __builtin_amdgcn_mfma_f32_16x16x32_bf16(a, b, acc2[t], 0, 0, 0);
        }
    }
#pragma unroll
    for (int t = 0; t < 8; ++t) {
        int col = t * 16 + l16;
        float bv = b2[col];
#pragma unroll
        for (int r = 0; r < 4; ++r) {
            int row = wave * 16 + quad * 4 + r;
            C[(rowBase + row) * 128 + col] = f2bf(fmaxf(acc2[t][r] + bv, 0.f));
        }
    }
}

// ---------------- MFMA node MLP: normalize + 128->32->32->32 ----------------
__global__ __launch_bounds__(256) void norm_mlp_mfma(const u16* __restrict__ X,
                                                     const u16* __restrict__ Wsm,
                                                     const float* __restrict__ bs1,
                                                     const float* __restrict__ bs2,
                                                     const float* __restrict__ bs3,
                                                     float* __restrict__ S) {
    __shared__ u16 As[64][136];      // normalized rows (bf16)
    __shared__ u16 W1s[32][136];     // Ws1t 32x128
    __shared__ u16 W23s[2][32][40];  // Ws2t, Ws3t 32x32
    __shared__ u16 H[64][40];        // hidden (wave-private 16-row strips)
    int tid = threadIdx.x, lane = tid & 63, wave = tid >> 6;
    int quad = lane >> 4, l16 = lane & 15;
    size_t rowBase = (size_t)blockIdx.x * 64;

#pragma unroll
    for (int i = 0; i < 2; ++i) {
        int c = tid + i * 256;
        int r = c >> 4, co = (c & 15) << 3;
        *(uint4*)&W1s[r][co] = *(const uint4*)(Wsm + r * 128 + co);
    }
    {
        int which = tid >> 7, cc = tid & 127;
        int r = cc >> 2, co = (cc & 3) << 3;
        *(uint4*)&W23s[which][r][co] = *(const uint4*)(Wsm + 4096 + which * 1024 + r * 32 + co);
    }

    const u32* Xu = (const u32*)X;
    for (int i = 0; i < 16; ++i) {
        int row = wave * 16 + i;
        u32 v = Xu[(rowBase + row) * 64 + lane];
        float f0 = bf2f((u16)v), f1 = bf2f((u16)(v >> 16));
        float ss = f0 * f0 + f1 * f1;
        for (int o = 1; o < 64; o <<= 1) ss += __shfl_xor(ss, o, 64);
        float inv = 1.0f / fmaxf(sqrtf(ss), 1e-12f);
        *(u32*)&As[row][2 * lane] = (u32)f2bf(f0 * inv) | ((u32)f2bf(f1 * inv) << 16);
    }
    __syncthreads();

    f32x4 acc[2];
    acc[0] = (f32x4){0.f, 0.f, 0.f, 0.f};
    acc[1] = (f32x4){0.f, 0.f, 0.f, 0.f};
#pragma unroll
    for (int c = 0; c < 4; ++c) {
        short8 a = *(const short8*)&As[wave * 16 + l16][c * 32 + quad * 8];
#pragma unroll
        for (int t = 0; t < 2; ++t) {
            short8 b = *(const short8*)&W1s[t * 16 + l16][c * 32 + quad * 8];
            acc[t] = __builtin_amdgcn_mfma_f32_16x16x32_bf16(a, b, acc[t], 0, 0, 0);
        }
    }
#pragma unroll
    for (int t = 0; t < 2; ++t) {
        int col = t * 16 + l16;
        float bv = bs1[col];
#pragma unroll
        for (int r = 0; r < 4; ++r)
            H[wave * 16 + quad * 4 + r][col] = f2bf(fmaxf(acc[t][r] + bv, 0.f));
    }
    __syncthreads();

    f32x4 acc2[2];
    acc2[0] = (f32x4){0.f, 0.f, 0.f, 0.f};
    acc2[1] = (f32x4){0.f, 0.f, 0.f, 0.f};
    {
        short8 a = *(const short8*)&H[wave * 16 + l16][quad * 8];
#pragma unroll
        for (int t = 0; t < 2; ++t) {
            short8 b = *(const short8*)&W23s[0][t * 16 + l16][quad * 8];
            acc2[t] = __builtin_amdgcn_mfma_f32_16x16x32_bf16(a, b, acc2[t], 0, 0, 0);
        }
    }
    __syncthreads();
#pragma unroll
    for (int t = 0; t < 2; ++t) {
        int col = t * 16 + l16;
        float bv = bs2[col];
#pragma unroll
        for (int r = 0; r < 4; ++r)
            H[wave * 16 + quad * 4 + r][col] = f2bf(fmaxf(acc2[t][r] + bv, 0.f));
    }
    __syncthreads();

    f32x4 acc3[2];
    acc3[0] = (f32x4){0.f, 0.f, 0.f, 0.f};
    acc3[1] = (f32x4){0.f, 0.f, 0.f, 0.f};
    {
        short8 a = *(const short8*)&H[wave * 16 + l16][quad * 8];
#pragma unroll
        for (int t = 0; t < 2; ++t) {
            short8 b = *(const short8*)&W23s[1][t * 16 + l16][quad * 8];
            acc3[t] = __builtin_amdgcn_mfma_f32_16x16x32_bf16(a, b, acc3[t], 0, 0, 0);
        }
    }
#pragma unroll
    for (int t = 0; t < 2; ++t) {
        int col = t * 16 + l16;
        float bv = bs3[col];
#pragma unroll
        for (int r = 0; r < 4; ++r) {
            int row = wave * 16 + quad * 4 + r;
            S[(rowBase + row) * 32 + col] = fmaxf(acc3[t][r] + bv, 0.f);
        }
    }
}

// ---------------- per-graph Gram: out[g][f][e] = sum_n S[g,n,f]*S[g,n,e] ----
__global__ __launch_bounds__(256) void gram(const float* __restrict__ S,
                                            float* __restrict__ out) {
    __shared__ float Sg[256 * 32];
    int t = threadIdx.x, g = blockIdx.x;
    const float4* src = (const float4*)(S + (size_t)g * 8192);
    float4* dst = (float4*)Sg;
    for (int i = 0; i < 8; ++i) dst[t + i * 256] = src[t + i * 256];
    __syncthreads();

    int f = t >> 3, e0 = (t & 7) << 2;
    float4 a = {0.f, 0.f, 0.f, 0.f};
    for (int n = 0; n < 256; ++n) {
        float sf = Sg[n * 32 + f];
        float4 se = *(const float4*)&Sg[n * 32 + e0];
        a.x += sf * se.x; a.y += sf * se.y; a.z += sf * se.z; a.w += sf * se.w;
    }
    *(float4*)(out + (size_t)g * 1024 + f * 32 + e0) = a;
}

// ---------------- per-graph MLP: 1024->32->32->2 (fp32) ----------------
__global__ __launch_bounds__(256) void graph_mlp(const float* __restrict__ HH,
                                                 const float* Wm1, const float* bm1,
                                                 const float* Wm2, const float* bm2,
                                                 const float* Wm3, const float* bm3,
                                                 float* __restrict__ out) {
    __shared__ float hh[1024];
    __shared__ float red[256];
    __shared__ float o1[32];
    __shared__ float o2[32];
    int t = threadIdx.x, g = blockIdx.x;
    ((float4*)hh)[t] = ((const float4*)(HH + (size_t)g * 1024))[t];
    __syncthreads();

    int j = t & 31, part = t >> 5;
    float p = 0.f;
    for (int i = 0; i < 128; ++i) { int k = part * 128 + i; p += hh[k] * Wm1[k * 32 + j]; }
    red[t] = p;
    __syncthreads();
    if (t < 32) {
        float s = 0.f;
        for (int q = 0; q < 8; ++q) s += red[q * 32 + t];
        o1[t] = fmaxf(s + bm1[t], 0.f);
    }
    __syncthreads();
    if (t < 32) {
        float s = 0.f;
        for (int k = 0; k < 32; ++k) s += o1[k] * Wm2[k * 32 + t];
        o2[t] = fmaxf(s + bm2[t], 0.f);
    }
    __syncthreads();
    if (t < 2) {
        float s = 0.f;
        for (int k = 0; k < 32; ++k) s += o2[k] * Wm3[k * 2 + t];
        out[524288 + g * 2 + t] = fmaxf(s + bm3[t], 0.f);
    }
}

// ---------------------------------------------------------------------------
extern "C" void kernel_launch(void* const* d_in, const int* in_sizes, int n_in,
                              void* d_out, int out_size, void* d_ws, size_t ws_size,
                              hipStream_t stream) {
    const float* x   = (const float*)d_in[0];
    const int*   ei  = (const int*)d_in[1];
    const float* W1a = (const float*)d_in[2];  const float* b1a = (const float*)d_in[3];
    const float* W2a = (const float*)d_in[4];  const float* b2a = (const float*)d_in[5];
    const float* W1b = (const float*)d_in[6];  const float* b1b = (const float*)d_in[7];
    const float* W2b = (const float*)d_in[8];  const float* b2b = (const float*)d_in[9];
    const float* Ws1 = (const float*)d_in[10]; const float* bs1 = (const float*)d_in[11];
    const float* Ws2 = (const float*)d_in[12]; const float* bs2 = (const float*)d_in[13];
    const float* Ws3 = (const float*)d_in[14]; const float* bs3 = (const float*)d_in[15];
    const float* Wm1 = (const float*)d_in[16]; const float* bm1 = (const float*)d_in[17];
    const float* Wm2 = (const float*)d_in[18]; const float* bm2 = (const float*)d_in[19];
    const float* Wm3 = (const float*)d_in[20]; const float* bm3 = (const float*)d_in[21];
    float* out = (float*)d_out;

    const int* gsrc = ei;
    const int* gdst = ei + NE;

    char* ws = (char*)d_ws;
    size_t off = 0;
    auto alloc = [&](size_t bytes) { size_t r = off; off = (off + bytes + 255) & ~(size_t)255; return r; };
    int*  cursor = (int*)(ws + alloc((size_t)NB * 4));
    int*  bcnt   = (int*)(ws + alloc((size_t)NB * 4));
    u32*  ebuf   = (u32*)(ws + alloc((size_t)NB * ECAP * 4));   // 10.5 MB
    int*  csr    = (int*)(ws + alloc((size_t)NB * CCAP * 4));   // 13.6 MB (adjacent)
    int*  stA    = (int*)(ws + alloc((size_t)NN * 4));
    int*  dgA    = (int*)(ws + alloc((size_t)NN * 4));
    u16*  Wt     = (u16*)(ws + alloc(4 * 16384 * 2));
    u16*  Wsm    = (u16*)(ws + alloc(6144 * 2));
    u16*  X0     = (u16*)(ws + alloc((size_t)(NN + 1) * 128 * 2));  // +zero row
    u16*  H1     = (u16*)(ws + alloc((size_t)(NN + 1) * 128 * 2));  // +zero row
    float* S     = (float*)ebuf;   // 16.78MB alias over ebuf+csr (dead by then)
    (void)ws_size; (void)n_in; (void)in_sizes; (void)out_size;

    // ---- build padded CSR once (edge structure identical for both layers) ----
    init_cursor<<<NB / 256, 256, 0, stream>>>(cursor);
    bin_scatter<<<NE / ECH, 256, 0, stream>>>(gsrc, gdst, cursor, ebuf);
    csr_sort<<<NB, 512, 0, stream>>>(ebuf, cursor, csr, stA, dgA, bcnt);

    // ---- casts / weight prep ----
    cast_x<<<NN * 128 / (256 * 8), 256, 0, stream>>>(x, X0);
    zero_tail<<<1, 128, 0, stream>>>(X0, H1);
    transpose_w<<<4, 256, 0, stream>>>(W1a, W2a, W1b, W2b, Wt);
    transpose_small<<<1, 256, 0, stream>>>(Ws1, Ws2, Ws3, Wsm);

    // ---- fused GINConv layers ----
    agg_mlp<<<NN / 128, 512, 0, stream>>>(X0, csr, stA, dgA, bcnt,
                                          Wt + 0 * 16384, Wt + 1 * 16384, b1a, b2a, H1);
    agg_mlp<<<NN / 128, 512, 0, stream>>>(H1, csr, stA, dgA, bcnt,
                                          Wt + 2 * 16384, Wt + 3 * 16384, b1b, b2b, X0);

    // ---- tail: MFMA node MLP, Gram -> out, graph MLP ----
    norm_mlp_mfma<<<NN / 64, 256, 0, stream>>>(X0, Wsm, bs1, bs2, bs3, S);
    gram<<<NG, 256, 0, stream>>>(S, out);
    graph_mlp<<<NG, 256, 0, stream>>>(out, Wm1, bm1, Wm2, bm2, Wm3, bm3, out);
}